// Round 9
// baseline (223.687 us; speedup 1.0000x reference)
//
#include <hip/hip_runtime.h>
#include <hip/hip_fp16.h>

#define NF 128     // feature dim, fixed by the problem
#define KC 64      // edge chunks for count histogram
#define NPART 4    // node partitions (N/4 ints fit LDS: 12500*4B = 50KB)
#define NPMAX 12544
#define DMAX 64    // fixed CSR stride (Poisson(16): P(deg>64) ~ 0; exact via ovf)

typedef _Float16 half8  __attribute__((ext_vector_type(8)));
typedef float    floatx4 __attribute__((ext_vector_type(4)));

// ---------------- prep_k: {count histogram} | {zero scnt} | {W transpose} -------
// Three independent block populations in one launch.
// count: block (c,p) histograms chunk c into partition p (LDS), writes uint8
// pcnt[c*N + node] (per-chunk count; mean 0.25 << 255). R6-proven code.
__global__ __launch_bounds__(512) void prep_k(
    const int* __restrict__ dst, unsigned char* __restrict__ pcnt,
    int* __restrict__ scnt, int E, int N, int Ec, int zb,
    const float* __restrict__ W1, const float* __restrict__ W2,
    __half* __restrict__ WT1, __half* __restrict__ WT2)
{
    __shared__ int lcnt[NPMAX];
    const int b = blockIdx.x;
    const int CB = KC * NPART;                 // 256 count blocks
    if (b < CB) {
        const int p = b & 3, c = b >> 2;
        const int Np = (N + 3) >> 2;
        const int lo = p * Np, hi = min(lo + Np, N);
        const int sz = hi - lo;
        for (int i = threadIdx.x; i < sz; i += 512) lcnt[i] = 0;
        __syncthreads();

        const int e0 = c * Ec, e1 = min(e0 + Ec, E);
        for (int e = e0 + (int)threadIdx.x * 4; e + 3 < e1; e += 512 * 4) {
            int4 d = *(const int4*)(dst + e);
            if (d.x >= lo && d.x < hi) atomicAdd(&lcnt[d.x - lo], 1);
            if (d.y >= lo && d.y < hi) atomicAdd(&lcnt[d.y - lo], 1);
            if (d.z >= lo && d.z < hi) atomicAdd(&lcnt[d.z - lo], 1);
            if (d.w >= lo && d.w < hi) atomicAdd(&lcnt[d.w - lo], 1);
        }
        int rem0 = e0 + ((e1 - e0) & ~3);
        for (int e = rem0 + (int)threadIdx.x; e < e1; e += 512) {
            int d = dst[e];
            if (d >= lo && d < hi) atomicAdd(&lcnt[d - lo], 1);
        }
        __syncthreads();
        for (int i = threadIdx.x; i < sz; i += 512)
            pcnt[(size_t)c * N + lo + i] = (unsigned char)lcnt[i];
        return;
    }
    if (b < CB + zb) {
        int i = (b - CB) * 512 + threadIdx.x;
        if (i <= N) scnt[i] = 0;               // scnt[N] = overflow counter
        return;
    }
    int idx = (b - CB - zb) * 512 + threadIdx.x;   // 0..32767
    const float* W = (idx < 16384) ? W1 : W2;
    __half* WT     = (idx < 16384) ? WT1 : WT2;
    int j = idx & 16383;
    int nn = j & 127, k = j >> 7;
    WT[nn * NF + k] = __float2half(W[k * NF + nn]);
}

// ---------------- mix_k: co-dispatched {CSR fill} + {gemm1 scaled} ---------------
// Fill (latency/scatter-bound) and gemm1 (MFMA-bound) are independent: gemm1
// gets deg from pcnt (prep_k product), NOT from fill's scnt. 1:4 interleave
// co-resides both populations per CU. gemm1 sums its 128 nodes' 64 pcnt bytes
// (coalesced byte loads), writes deg[] for aggmm/agg4, and writes H16 directly
// as fp16(acc * rsqrt(deg+1)) — identical numerics to the R6/R7 path.
__device__ __forceinline__ void gemm1_body(
    const float* __restrict__ X, const __half* __restrict__ WT,
    const unsigned char* __restrict__ pcnt, int* __restrict__ deg,
    __half* __restrict__ H, int M, int bid,
    __half (*wlds)[136], int* degl)
{
    const int tid = threadIdx.x;
    {   // stage WT (128x128 halves): 4 threads/row, 32 halves each
        int r = tid >> 2;
        int c0 = (tid & 3) * 32;
        const half8* s = (const half8*)(WT + (size_t)r * NF + c0);
        half8* d = (half8*)&wlds[r][c0];
        #pragma unroll
        for (int j = 0; j < 4; j++) d[j] = s[j];
    }
    // degree for this block's 128 nodes: thread t<128 sums 64 chunk-counts
    // (per c, lanes read 128 consecutive bytes -> coalesced)
    if (tid < 128) {
        int nd = bid * 128 + tid;
        int dt = 0;
        if (nd < M) {
            #pragma unroll 8
            for (int c = 0; c < KC; c++) dt += pcnt[(size_t)c * M + nd];
            deg[nd] = dt;
        }
        degl[tid] = dt;
    }
    __syncthreads();

    const int wave = tid >> 6, lane = tid & 63;
    const int quad = lane >> 4, l15 = lane & 15;
    const int rowA = bid * 128 + wave * 16 + l15;
    const int rowc = (rowA < M) ? rowA : (M - 1);

    half8 afr[4];
    #pragma unroll
    for (int kc = 0; kc < 4; kc++) {
        const floatx4* p = (const floatx4*)(X + (size_t)rowc * NF + kc * 32 + quad * 8);
        floatx4 u = p[0], v = p[1];
        half8 a;
        a[0] = (_Float16)u[0]; a[1] = (_Float16)u[1];
        a[2] = (_Float16)u[2]; a[3] = (_Float16)u[3];
        a[4] = (_Float16)v[0]; a[5] = (_Float16)v[1];
        a[6] = (_Float16)v[2]; a[7] = (_Float16)v[3];
        afr[kc] = a;
    }

    floatx4 acc[8];
    #pragma unroll
    for (int ct = 0; ct < 8; ct++) { floatx4 z = {0.f, 0.f, 0.f, 0.f}; acc[ct] = z; }

    #pragma unroll
    for (int kc = 0; kc < 4; kc++) {
        #pragma unroll
        for (int ct = 0; ct < 8; ct++) {
            half8 b = *(const half8*)&wlds[ct * 16 + l15][kc * 32 + quad * 8];
            acc[ct] = __builtin_amdgcn_mfma_f32_16x16x32_f16(afr[kc], b, acc[ct], 0, 0, 0);
        }
    }

    const int lrow0 = wave * 16 + quad * 4;
    #pragma unroll
    for (int r = 0; r < 4; r++) {
        int orow = bid * 128 + lrow0 + r;
        if (orow < M) {
            float dv = rsqrtf((float)degl[lrow0 + r] + 1.0f);
            #pragma unroll
            for (int ct = 0; ct < 8; ct++)
                H[(size_t)orow * NF + ct * 16 + l15] = __float2half(acc[ct][r] * dv);
        }
    }
}

__global__ __launch_bounds__(512) void mix_k(
    const int* __restrict__ src, const int* __restrict__ dst,
    int* __restrict__ scnt, int* __restrict__ csrF, int* __restrict__ ovf,
    int E, int N,
    const float* __restrict__ X, const __half* __restrict__ WT,
    const unsigned char* __restrict__ pcnt, int* __restrict__ deg,
    __half* __restrict__ H16, int GB)
{
    __shared__ __half wlds[128][136];
    __shared__ int degl[128];
    const int b = blockIdx.x;
    const bool isGemm = ((b % 5) == 0) && (b / 5 < GB);
    if (isGemm) {
        gemm1_body(X, WT, pcnt, deg, H16, N, b / 5, wlds, degl);
        return;
    }
    const int fid = (b < 5 * GB) ? (b - (b / 5 + 1)) : (b - GB);
    int e = fid * 512 + (int)threadIdx.x;
    if (e < E) {
        int d = dst[e], s = src[e];
        int pos = atomicAdd(&scnt[d], 1);
        if (pos < DMAX) {
            __builtin_nontemporal_store(s, &csrF[(size_t)d * DMAX + pos]);
        } else {
            int o = atomicAdd(&scnt[N], 1);
            ovf[2 * o] = d; ovf[2 * o + 1] = s;
        }
    }
}

// ---------------- gather2w: 2 nodes/wave, 16B/lane loads (R6 champion) ----------
__device__ __forceinline__ void gather2w(
    const half8* __restrict__ hs8, const int* __restrict__ csrF,
    const int* __restrict__ deg, int nA, int n,
    int g, int fl, int lane, floatx4& ac0, floatx4& ac1,
    const int* __restrict__ ovf, int novf)
{
    const int ep  = g & 1;        // edge parity
    const int isB = g >> 1;       // which node this lane group serves
    const int nB  = nA + 1;

    int cntA = (nA < n) ? deg[nA] : 0;
    int cntB = (nB < n) ? deg[nB] : 0;
    const int ccA = min(cntA, DMAX), ccB = min(cntB, DMAX);

    int idxA = (lane < ccA) ? __builtin_nontemporal_load(&csrF[(size_t)nA * DMAX + lane]) : 0;
    int idxB = (lane < ccB) ? __builtin_nontemporal_load(&csrF[(size_t)nB * DMAX + lane]) : 0;

    // self-loops (parity-0 groups only; each group adds its own node's row)
    if (ep == 0) {
        int nd = isB ? nB : nA;
        if (nd < n) {
            half8 s = hs8[(size_t)nd * 16 + fl];
            ac0[0] += (float)s[0]; ac0[1] += (float)s[1];
            ac0[2] += (float)s[2]; ac0[3] += (float)s[3];
            ac1[0] += (float)s[4]; ac1[1] += (float)s[5];
            ac1[2] += (float)s[6]; ac1[3] += (float)s[7];
        }
    }

    const int myc  = isB ? ccB : ccA;
    const int maxc = max(ccA, ccB);
    for (int j = 0; j < maxc; j += 16) {   // 16 edges/node per batch, 8 loads deep
        int s[8];
        half8 v[8];
        #pragma unroll
        for (int t = 0; t < 8; t++) {
            int e = j + 2 * t + ep;
            int eA = min(e, ccA - 1); eA = (eA < 0) ? 0 : eA;
            int eB = min(e, ccB - 1); eB = (eB < 0) ? 0 : eB;
            int sa = __shfl(idxA, eA, 64);
            int sb = __shfl(idxB, eB, 64);
            s[t] = isB ? sb : sa;
        }
        #pragma unroll
        for (int t = 0; t < 8; t++)
            v[t] = hs8[(size_t)s[t] * 16 + fl];
        #pragma unroll
        for (int t = 0; t < 8; t++) {
            if (j + 2 * t + ep < myc) {
                ac0[0] += (float)v[t][0]; ac0[1] += (float)v[t][1];
                ac0[2] += (float)v[t][2]; ac0[3] += (float)v[t][3];
                ac1[0] += (float)v[t][4]; ac1[1] += (float)v[t][5];
                ac1[2] += (float)v[t][6]; ac1[3] += (float)v[t][7];
            }
        }
    }

    // exact-correctness overflow path (deg > DMAX) — empty in practice
    if (novf > 0 && ep == 0) {
        int myN = isB ? nB : nA;
        for (int i = 0; i < novf; i++) {
            int d = ovf[2 * i];
            if (d == myN) {
                half8 v = hs8[(size_t)ovf[2 * i + 1] * 16 + fl];
                ac0[0] += (float)v[0]; ac0[1] += (float)v[1];
                ac0[2] += (float)v[2]; ac0[3] += (float)v[3];
                ac1[0] += (float)v[4]; ac1[1] += (float)v[5];
                ac1[2] += (float)v[6]; ac1[3] += (float)v[7];
            }
        }
    }

    // combine parity halves: xor16 pairs g0<->g1 (node A) and g2<->g3 (node B)
    #pragma unroll
    for (int q = 0; q < 4; q++) {
        ac0[q] += __shfl_xor(ac0[q], 16, 64);
        ac1[q] += __shfl_xor(ac1[q], 16, 64);
    }
}

// ---------------- aggmm: fused agg(layer1) + gemm2; 512 thr, 16 nodes/block -----
__global__ __launch_bounds__(512) void aggmm_k(
    const __half* __restrict__ hs, const int* __restrict__ csrF,
    const int* __restrict__ deg, const int* __restrict__ scnt,
    const float* __restrict__ bias, const __half* __restrict__ WT,
    __half* __restrict__ Hout, int n, const int* __restrict__ ovf)
{
    __shared__ __half alds[16][136];
    const int tid = threadIdx.x;
    const int wave = tid >> 6, lane = tid & 63;
    const int g = lane >> 4, fl = lane & 15;
    const int nb0 = blockIdx.x * 16;
    const int nA = nb0 + wave * 2;
    const int novf = scnt[n];

    floatx4 ac0 = {0.f, 0.f, 0.f, 0.f}, ac1 = {0.f, 0.f, 0.f, 0.f};
    gather2w((const half8*)hs, csrF, deg, nA, n, g, fl, lane, ac0, ac1, ovf, novf);

    if ((g & 1) == 0) {   // groups 0 (node A) and 2 (node B) write
        int node = nA + (g >> 1);
        int row  = wave * 2 + (g >> 1);
        half8 hv;
        if (node < n) {
            float dv = rsqrtf((float)deg[node] + 1.0f);
            const floatx4 bv0 = *(const floatx4*)&bias[fl * 8];
            const floatx4 bv1 = *(const floatx4*)&bias[fl * 8 + 4];
            hv[0] = (_Float16)fmaxf(dv * ac0[0] + bv0[0], 0.f);
            hv[1] = (_Float16)fmaxf(dv * ac0[1] + bv0[1], 0.f);
            hv[2] = (_Float16)fmaxf(dv * ac0[2] + bv0[2], 0.f);
            hv[3] = (_Float16)fmaxf(dv * ac0[3] + bv0[3], 0.f);
            hv[4] = (_Float16)fmaxf(dv * ac1[0] + bv1[0], 0.f);
            hv[5] = (_Float16)fmaxf(dv * ac1[1] + bv1[1], 0.f);
            hv[6] = (_Float16)fmaxf(dv * ac1[2] + bv1[2], 0.f);
            hv[7] = (_Float16)fmaxf(dv * ac1[3] + bv1[3], 0.f);
        } else {
            #pragma unroll
            for (int i = 0; i < 8; i++) hv[i] = (_Float16)0.f;
        }
        *(half8*)&alds[row][fl * 8] = hv;
    }
    __syncthreads();

    // 16x128 output tile: wave w owns col-tile ct = w (16 cols)
    const int quad = lane >> 4, l15 = lane & 15;
    const int ct = wave;
    half8 afr[4];
    #pragma unroll
    for (int kc = 0; kc < 4; kc++)
        afr[kc] = *(const half8*)&alds[l15][kc * 32 + quad * 8];

    floatx4 o0 = {0.f, 0.f, 0.f, 0.f};
    #pragma unroll
    for (int kc = 0; kc < 4; kc++) {
        half8 b = *(const half8*)(WT + (size_t)(ct * 16 + l15) * NF + kc * 32 + quad * 8);
        o0 = __builtin_amdgcn_mfma_f32_16x16x32_f16(afr[kc], b, o0, 0, 0, 0);
    }

    #pragma unroll
    for (int r = 0; r < 4; r++) {
        int node = nb0 + quad * 4 + r;
        if (node < n) {
            float dv = rsqrtf((float)deg[node] + 1.0f);
            Hout[(size_t)node * NF + ct * 16 + l15] = __float2half(o0[r] * dv);
        }
    }
}

// ---------------- agg4: final aggregate (fp32 out); 256 thr, 8 nodes/block ------
__global__ __launch_bounds__(256) void agg4_k(
    const __half* __restrict__ hs, const int* __restrict__ csrF,
    const int* __restrict__ deg, const int* __restrict__ scnt,
    const float* __restrict__ bias, float* __restrict__ outf, int n,
    const int* __restrict__ ovf)
{
    const int tid = threadIdx.x;
    const int wave = tid >> 6, lane = tid & 63;
    const int g = lane >> 4, fl = lane & 15;
    const int nA = blockIdx.x * 8 + wave * 2;
    if (nA >= n) return;
    const int novf = scnt[n];

    floatx4 ac0 = {0.f, 0.f, 0.f, 0.f}, ac1 = {0.f, 0.f, 0.f, 0.f};
    gather2w((const half8*)hs, csrF, deg, nA, n, g, fl, lane, ac0, ac1, ovf, novf);

    if ((g & 1) == 0) {
        int node = nA + (g >> 1);
        if (node < n) {
            float dv = rsqrtf((float)deg[node] + 1.0f);
            const floatx4 bv0 = *(const floatx4*)&bias[fl * 8];
            const floatx4 bv1 = *(const floatx4*)&bias[fl * 8 + 4];
            floatx4 w0, w1;
            w0[0] = dv * ac0[0] + bv0[0]; w0[1] = dv * ac0[1] + bv0[1];
            w0[2] = dv * ac0[2] + bv0[2]; w0[3] = dv * ac0[3] + bv0[3];
            w1[0] = dv * ac1[0] + bv1[0]; w1[1] = dv * ac1[1] + bv1[1];
            w1[2] = dv * ac1[2] + bv1[2]; w1[3] = dv * ac1[3] + bv1[3];
            *(floatx4*)(outf + (size_t)node * NF + fl * 8)     = w0;
            *(floatx4*)(outf + (size_t)node * NF + fl * 8 + 4) = w1;
        }
    }
}

// ---------------- launch ----------------

extern "C" void kernel_launch(void* const* d_in, const int* in_sizes, int n_in,
                              void* d_out, int out_size, void* d_ws, size_t ws_size,
                              hipStream_t stream) {
    const float* x  = (const float*)d_in[0];
    const int*   ei = (const int*)d_in[1];
    const float* W1 = (const float*)d_in[2];
    const float* b1 = (const float*)d_in[3];
    const float* W2 = (const float*)d_in[4];
    const float* b2 = (const float*)d_in[5];
    float* out = (float*)d_out;

    const int N = in_sizes[0] / NF;   // 50000
    const int E = in_sizes[1] / 2;    // 800000
    const int* src = ei;
    const int* dst = ei + E;

    char* ws = (char*)d_ws;
    size_t off = 0;
    auto alloc = [&](size_t bytes) {
        void* p = ws + off;
        off += bytes;
        off = (off + 63) & ~(size_t)63;
        return p;
    };
    unsigned char* pcnt = (unsigned char*)alloc((size_t)KC * N);  // chunk counts
    int*    scnt = (int*)alloc((size_t)(N + 1) * 4);    // fill cursors + ovf ctr
    int*    deg  = (int*)alloc((size_t)N * 4);          // degrees (gemm1 product)
    int*    csrF = (int*)alloc((size_t)N * DMAX * 4);   // fixed-stride CSR
    int*    ovf  = (int*)alloc((size_t)E * 2 * 4);      // exact overflow list
    __half* WT1  = (__half*)alloc((size_t)NF * NF * 2);
    __half* WT2  = (__half*)alloc((size_t)NF * NF * 2);
    __half* H16  = (__half*)alloc((size_t)N * NF * 2);
    __half* A16  = (__half*)alloc((size_t)N * NF * 2);

    int Ec  = (((E + KC - 1) / KC) + 3) & ~3;  // chunk size, multiple of 4
    int zb  = (N + 1 + 511) / 512;             // zero-blocks (512 thr)
    int tb  = 64;                              // transpose blocks (32768/512)
    int GB  = (N + 127) / 128;                 // gemm1 blocks (512 thr)
    int fb  = (E + 511) / 512;                 // fill blocks (1 edge/thread)
    int mb  = (N + 15) / 16;                   // aggmm blocks (16 nodes, 512 thr)
    int ab  = (N + 7) / 8;                     // agg4 blocks (8 nodes, 256 thr)

    // count histogram | zero cursors | W transpose  (one launch)
    prep_k<<<KC * NPART + zb + tb, 512, 0, stream>>>(
        dst, pcnt, scnt, E, N, Ec, zb, W1, W2, WT1, WT2);
    // CSR fill (atomic cursors, NT stores) || gemm1 (deg from pcnt, scaled H16)
    mix_k<<<GB + fb, 512, 0, stream>>>(src, dst, scnt, csrF, ovf, E, N,
                                       x, WT1, pcnt, deg, H16, GB);
    // fused layer-1 aggregate + layer-2 GEMM
    aggmm_k<<<mb, 512, 0, stream>>>(H16, csrF, deg, scnt, b1, WT2, A16, N, ovf);
    // final aggregate -> fp32 output
    agg4_k<<<ab, 256, 0, stream>>>(A16, csrF, deg, scnt, b2, out, N, ovf);
}

// Round 10
// 204.679 us; speedup vs baseline: 1.0929x; 1.0929x over previous
//
#include <hip/hip_runtime.h>
#include <hip/hip_fp16.h>

#define NF 128    // feature dim, fixed by the problem
#define KC 64     // edge chunks
#define NPART 4   // node partitions (N/4 ints must fit LDS: 12500*4B = 50KB)
#define NPMAX 12544

typedef _Float16 half8  __attribute__((ext_vector_type(8)));
typedef _Float16 half4v __attribute__((ext_vector_type(4)));
typedef float    floatx4 __attribute__((ext_vector_type(4)));

// ---------------- count2: LDS histogram per (chunk, partition) -------------------
__global__ __launch_bounds__(512) void count2_k(
    const int* __restrict__ dst, unsigned char* __restrict__ pcnt,
    int E, int N, int Ec)
{
    __shared__ int lcnt[NPMAX];
    const int p = blockIdx.x & 3, c = blockIdx.x >> 2;
    const int Np = (N + 3) >> 2;
    const int lo = p * Np, hi = min(lo + Np, N);
    const int sz = hi - lo;
    for (int i = threadIdx.x; i < sz; i += 512) lcnt[i] = 0;
    __syncthreads();

    const int e0 = c * Ec, e1 = min(e0 + Ec, E);
    for (int e = e0 + (int)threadIdx.x * 4; e + 3 < e1; e += 512 * 4) {
        int4 d = *(const int4*)(dst + e);
        if (d.x >= lo && d.x < hi) atomicAdd(&lcnt[d.x - lo], 1);
        if (d.y >= lo && d.y < hi) atomicAdd(&lcnt[d.y - lo], 1);
        if (d.z >= lo && d.z < hi) atomicAdd(&lcnt[d.z - lo], 1);
        if (d.w >= lo && d.w < hi) atomicAdd(&lcnt[d.w - lo], 1);
    }
    int rem0 = e0 + ((e1 - e0) & ~3);
    for (int e = rem0 + (int)threadIdx.x; e < e1; e += 512) {
        int d = dst[e];
        if (d >= lo && d < hi) atomicAdd(&lcnt[d - lo], 1);
    }
    __syncthreads();
    for (int i = threadIdx.x; i < sz; i += 512)
        pcnt[(size_t)c * N + lo + i] = (unsigned char)lcnt[i];
}

// ---------------- pscan2 (+fused W-transpose) ------------------------------------
__global__ __launch_bounds__(256) void pscan2_k(
    unsigned char* __restrict__ pcnt, float* __restrict__ dinv,
    int* __restrict__ rowptr, int* __restrict__ blocksum, int n, int N, int nb,
    const float* __restrict__ W1, const float* __restrict__ W2,
    __half* __restrict__ WT1, __half* __restrict__ WT2)
{
    if ((int)blockIdx.x >= nb) {
        int idx = ((int)blockIdx.x - nb) * 256 + threadIdx.x;   // 0..32767
        const float* W = (idx < 16384) ? W1 : W2;
        __half* WT     = (idx < 16384) ? WT1 : WT2;
        int j = idx & 16383;
        int nn = j & 127, k = j >> 7;
        WT[nn * NF + k] = __float2half(W[k * NF + nn]);
        return;
    }
    __shared__ int sm[256];
    int tid = threadIdx.x;
    int bin = blockIdx.x * 256 + tid;
    int total = 0;
    if (bin < n) {
        #pragma unroll 4
        for (int c = 0; c < KC; c++) {
            size_t o = (size_t)c * N + bin;
            int v = pcnt[o];
            pcnt[o] = (unsigned char)total;   // exclusive chunk prefix (coff)
            total += v;
        }
        dinv[bin] = rsqrtf((float)total + 1.0f);  // +1 = self-loop
    }
    sm[tid] = total;
    __syncthreads();
    #pragma unroll
    for (int d = 1; d < 256; d <<= 1) {
        int t = (tid >= d) ? sm[tid - d] : 0;
        __syncthreads();
        sm[tid] += t;
        __syncthreads();
    }
    if (bin < n) rowptr[bin] = sm[tid] - total;    // local exclusive prefix
    if (tid == 255) blocksum[blockIdx.x] = sm[255];
}

// ---------------- MFMA GEMM body (512 threads, 128 rows/block) -------------------
template<bool F32IN>
__device__ __forceinline__ void gemm_body512(
    const void* __restrict__ Xv, const __half* __restrict__ WT,
    const float* __restrict__ dinv, __half* __restrict__ out, int M, int bid,
    __half (*wlds)[136])
{
    const int tid = threadIdx.x;
    {   // stage WT (128x128 halves): 4 threads/row, 32 halves each
        int r = tid >> 2;
        int c0 = (tid & 3) * 32;
        const half8* s = (const half8*)(WT + (size_t)r * NF + c0);
        half8* d = (half8*)&wlds[r][c0];
        #pragma unroll
        for (int j = 0; j < 4; j++) d[j] = s[j];
    }
    __syncthreads();

    const int wave = tid >> 6, lane = tid & 63;
    const int quad = lane >> 4, l15 = lane & 15;
    const int rowA = bid * 128 + wave * 16 + l15;
    const int rowc = (rowA < M) ? rowA : (M - 1);

    half8 afr[4];
    if (F32IN) {
        const float* X = (const float*)Xv;
        #pragma unroll
        for (int kc = 0; kc < 4; kc++) {
            const floatx4* p = (const floatx4*)(X + (size_t)rowc * NF + kc * 32 + quad * 8);
            floatx4 u = p[0], v = p[1];
            half8 a;
            a[0] = (_Float16)u[0]; a[1] = (_Float16)u[1];
            a[2] = (_Float16)u[2]; a[3] = (_Float16)u[3];
            a[4] = (_Float16)v[0]; a[5] = (_Float16)v[1];
            a[6] = (_Float16)v[2]; a[7] = (_Float16)v[3];
            afr[kc] = a;
        }
    } else {
        const __half* X = (const __half*)Xv;
        #pragma unroll
        for (int kc = 0; kc < 4; kc++)
            afr[kc] = *(const half8*)(X + (size_t)rowc * NF + kc * 32 + quad * 8);
    }

    floatx4 acc[8];
    #pragma unroll
    for (int ct = 0; ct < 8; ct++) { floatx4 z = {0.f, 0.f, 0.f, 0.f}; acc[ct] = z; }

    #pragma unroll
    for (int kc = 0; kc < 4; kc++) {
        #pragma unroll
        for (int ct = 0; ct < 8; ct++) {
            half8 b = *(const half8*)&wlds[ct * 16 + l15][kc * 32 + quad * 8];
            acc[ct] = __builtin_amdgcn_mfma_f32_16x16x32_f16(afr[kc], b, acc[ct], 0, 0, 0);
        }
    }

    const int orow0 = bid * 128 + wave * 16 + quad * 4;
    #pragma unroll
    for (int r = 0; r < 4; r++) {
        int orow = orow0 + r;
        if (orow < M) {
            float s = dinv[orow];
            #pragma unroll
            for (int ct = 0; ct < 8; ct++)
                out[(size_t)orow * NF + ct * 16 + l15] = __float2half(acc[ct][r] * s);
        }
    }
}

// ---------------- mid_k: fused gemm1 + fill (+add_off) ---------------------------
__global__ __launch_bounds__(512) void mid_k(
    const int* __restrict__ src, const int* __restrict__ dst,
    const int* __restrict__ rowptr, const unsigned char* __restrict__ coff,
    const int* __restrict__ blocksum, int* __restrict__ rowptr2,
    int* __restrict__ csr, int E, int N, int Ec, int nb,
    const float* __restrict__ X, const __half* __restrict__ WT,
    const float* __restrict__ dinv, __half* __restrict__ H, int GB2)
{
    __shared__ __align__(16) char smem[NPMAX * 4 + 1024];   // 51.2KB union
    const int tid = threadIdx.x;
    if ((int)blockIdx.x < GB2) {
        gemm_body512<true>(X, WT, dinv, H, N, blockIdx.x, (__half(*)[136])smem);
        return;
    }
    int* lcur = (int*)smem;
    int* pref = (int*)(smem + NPMAX * 4);

    const int b = blockIdx.x - GB2;
    const int p = b & 3, c = b >> 2;
    const int Np = (N + 3) >> 2;
    const int lo = p * Np, hi = min(lo + Np, N);
    const int sz = hi - lo;

    // exclusive prefix of blocksum[0..nb) in pref
    int v = (tid < nb) ? blocksum[tid] : 0;
    if (tid < 256) pref[tid] = v;
    __syncthreads();
    #pragma unroll
    for (int d = 1; d < 256; d <<= 1) {
        int t = (tid < 256 && tid >= d) ? pref[tid - d] : 0;
        __syncthreads();
        if (tid < 256) pref[tid] += t;
        __syncthreads();
    }
    if (tid < 256) pref[tid] -= v;
    __syncthreads();

    for (int i = tid; i < sz; i += 512) {
        int bin = lo + i;
        int r = rowptr[bin] + pref[bin >> 8] + (int)coff[(size_t)c * N + bin];
        lcur[i] = r;
        if (c == 0) rowptr2[bin] = r;
    }
    if (c == 0 && p == 0 && tid == 0) rowptr2[N] = E;
    __syncthreads();

    const int e0 = c * Ec, e1 = min(e0 + Ec, E);
    for (int e = e0 + tid * 4; e + 3 < e1; e += 512 * 4) {
        int4 d = *(const int4*)(dst + e);
        int4 s = *(const int4*)(src + e);
        if (d.x >= lo && d.x < hi) csr[atomicAdd(&lcur[d.x - lo], 1)] = s.x;
        if (d.y >= lo && d.y < hi) csr[atomicAdd(&lcur[d.y - lo], 1)] = s.y;
        if (d.z >= lo && d.z < hi) csr[atomicAdd(&lcur[d.z - lo], 1)] = s.z;
        if (d.w >= lo && d.w < hi) csr[atomicAdd(&lcur[d.w - lo], 1)] = s.w;
    }
    int rem0 = e0 + ((e1 - e0) & ~3);
    for (int e = rem0 + tid; e < e1; e += 512) {
        int d = dst[e];
        if (d >= lo && d < hi) csr[atomicAdd(&lcur[d - lo], 1)] = src[e];
    }
}

// ---------------- gather2w: 2 nodes/wave, 16B/lane loads, champion structure -----
// R13-champion loop shape (s[8]/v[8] static unroll — proven spill-free) but each
// load is half8 (16B/lane): one instruction covers 4 rows (2 edges x 2 nodes),
// so the 8-deep batch holds 8KB/wave in flight (2x champion) at the same queue
// depth and ~same register count. Lane groups: g=lane>>4; {0,1}=node A parity
// {0,1}; {2,3}=node B. fl=lane&15 covers features fl*8..fl*8+7.
__device__ __forceinline__ void gather2w(
    const half8* __restrict__ hs8, const int* __restrict__ csr,
    const int* __restrict__ rowptr, int nA, int n,
    int g, int fl, int lane, floatx4& ac0, floatx4& ac1)
{
    const int ep  = g & 1;        // edge parity
    const int isB = g >> 1;       // which node this lane group serves
    const int nB  = nA + 1;

    int baseA = 0, cntA = 0, baseB = 0, cntB = 0;
    if (nA < n) {
        baseA = rowptr[nA];
        int mid = rowptr[nA + 1];
        cntA = mid - baseA;
        if (nB < n) { baseB = mid; cntB = rowptr[nB + 1] - mid; }
    }
    const int ccA = min(cntA, 64), ccB = min(cntB, 64);

    int idxA = (lane < ccA) ? __builtin_nontemporal_load(&csr[baseA + lane]) : 0;
    int idxB = (lane < ccB) ? __builtin_nontemporal_load(&csr[baseB + lane]) : 0;

    // self-loops (parity-0 groups only; each group adds its own node's row)
    if (ep == 0) {
        int nd = isB ? nB : nA;
        if (nd < n) {
            half8 s = hs8[(size_t)nd * 16 + fl];
            ac0[0] += (float)s[0]; ac0[1] += (float)s[1];
            ac0[2] += (float)s[2]; ac0[3] += (float)s[3];
            ac1[0] += (float)s[4]; ac1[1] += (float)s[5];
            ac1[2] += (float)s[6]; ac1[3] += (float)s[7];
        }
    }

    const int myc  = isB ? ccB : ccA;
    const int maxc = max(ccA, ccB);
    for (int j = 0; j < maxc; j += 16) {   // 16 edges/node per batch, 8 loads deep
        int s[8];
        half8 v[8];
        #pragma unroll
        for (int t = 0; t < 8; t++) {
            int e = j + 2 * t + ep;
            int eA = min(e, ccA - 1); eA = (eA < 0) ? 0 : eA;
            int eB = min(e, ccB - 1); eB = (eB < 0) ? 0 : eB;
            int sa = __shfl(idxA, eA, 64);
            int sb = __shfl(idxB, eB, 64);
            s[t] = isB ? sb : sa;
        }
        #pragma unroll
        for (int t = 0; t < 8; t++)
            v[t] = hs8[(size_t)s[t] * 16 + fl];
        #pragma unroll
        for (int t = 0; t < 8; t++) {
            if (j + 2 * t + ep < myc) {
                ac0[0] += (float)v[t][0]; ac0[1] += (float)v[t][1];
                ac0[2] += (float)v[t][2]; ac0[3] += (float)v[t][3];
                ac1[0] += (float)v[t][4]; ac1[1] += (float)v[t][5];
                ac1[2] += (float)v[t][6]; ac1[3] += (float)v[t][7];
            }
        }
    }

    // tails (cnt>64: ~never at Poisson(16)) — same body, idx reloaded per chunk
    const int cmax = max(cntA, cntB);
    for (int off = 64; off < cmax; off += 64) {
        int cA2 = cntA - off; cA2 = (cA2 < 0) ? 0 : min(cA2, 64);
        int cB2 = cntB - off; cB2 = (cB2 < 0) ? 0 : min(cB2, 64);
        int iA2 = (lane < cA2) ? csr[baseA + off + lane] : 0;
        int iB2 = (lane < cB2) ? csr[baseB + off + lane] : 0;
        int myc2 = isB ? cB2 : cA2;
        int m2   = max(cA2, cB2);
        for (int j = 0; j < m2; j += 16) {
            int s[8];
            half8 v[8];
            #pragma unroll
            for (int t = 0; t < 8; t++) {
                int e = j + 2 * t + ep;
                int eA = min(e, cA2 - 1); eA = (eA < 0) ? 0 : eA;
                int eB = min(e, cB2 - 1); eB = (eB < 0) ? 0 : eB;
                int sa = __shfl(iA2, eA, 64);
                int sb = __shfl(iB2, eB, 64);
                s[t] = isB ? sb : sa;
            }
            #pragma unroll
            for (int t = 0; t < 8; t++)
                v[t] = hs8[(size_t)s[t] * 16 + fl];
            #pragma unroll
            for (int t = 0; t < 8; t++) {
                if (j + 2 * t + ep < myc2) {
                    ac0[0] += (float)v[t][0]; ac0[1] += (float)v[t][1];
                    ac0[2] += (float)v[t][2]; ac0[3] += (float)v[t][3];
                    ac1[0] += (float)v[t][4]; ac1[1] += (float)v[t][5];
                    ac1[2] += (float)v[t][6]; ac1[3] += (float)v[t][7];
                }
            }
        }
    }

    // combine parity halves: xor16 pairs g0<->g1 (node A) and g2<->g3 (node B)
    #pragma unroll
    for (int q = 0; q < 4; q++) {
        ac0[q] += __shfl_xor(ac0[q], 16, 64);
        ac1[q] += __shfl_xor(ac1[q], 16, 64);
    }
}

// ---------------- aggmm: fused agg(layer1) + gemm2; 512 thr, 16 nodes/block -----
__global__ __launch_bounds__(512) void aggmm_k(
    const __half* __restrict__ hs, const int* __restrict__ rowptr,
    const int* __restrict__ csr, const float* __restrict__ dinv,
    const float* __restrict__ bias, const __half* __restrict__ WT,
    __half* __restrict__ Hout, int n)
{
    __shared__ __half alds[16][136];
    const int tid = threadIdx.x;
    const int wave = tid >> 6, lane = tid & 63;
    const int g = lane >> 4, fl = lane & 15;
    const int nb0 = blockIdx.x * 16;
    const int nA = nb0 + wave * 2;

    floatx4 ac0 = {0.f, 0.f, 0.f, 0.f}, ac1 = {0.f, 0.f, 0.f, 0.f};
    gather2w((const half8*)hs, csr, rowptr, nA, n, g, fl, lane, ac0, ac1);

    if ((g & 1) == 0) {   // groups 0 (node A) and 2 (node B) write
        int node = nA + (g >> 1);
        int row  = wave * 2 + (g >> 1);
        half8 hv;
        if (node < n) {
            float dv = dinv[node];
            const floatx4 bv0 = *(const floatx4*)&bias[fl * 8];
            const floatx4 bv1 = *(const floatx4*)&bias[fl * 8 + 4];
            hv[0] = (_Float16)fmaxf(dv * ac0[0] + bv0[0], 0.f);
            hv[1] = (_Float16)fmaxf(dv * ac0[1] + bv0[1], 0.f);
            hv[2] = (_Float16)fmaxf(dv * ac0[2] + bv0[2], 0.f);
            hv[3] = (_Float16)fmaxf(dv * ac0[3] + bv0[3], 0.f);
            hv[4] = (_Float16)fmaxf(dv * ac1[0] + bv1[0], 0.f);
            hv[5] = (_Float16)fmaxf(dv * ac1[1] + bv1[1], 0.f);
            hv[6] = (_Float16)fmaxf(dv * ac1[2] + bv1[2], 0.f);
            hv[7] = (_Float16)fmaxf(dv * ac1[3] + bv1[3], 0.f);
        } else {
            #pragma unroll
            for (int i = 0; i < 8; i++) hv[i] = (_Float16)0.f;
        }
        *(half8*)&alds[row][fl * 8] = hv;
    }
    __syncthreads();

    // 16x128 output tile: wave w owns col-tile ct = w (16 cols)
    const int quad = lane >> 4, l15 = lane & 15;
    const int ct = wave;
    half8 afr[4];
    #pragma unroll
    for (int kc = 0; kc < 4; kc++)
        afr[kc] = *(const half8*)&alds[l15][kc * 32 + quad * 8];

    floatx4 o0 = {0.f, 0.f, 0.f, 0.f};
    #pragma unroll
    for (int kc = 0; kc < 4; kc++) {
        half8 b = *(const half8*)(WT + (size_t)(ct * 16 + l15) * NF + kc * 32 + quad * 8);
        o0 = __builtin_amdgcn_mfma_f32_16x16x32_f16(afr[kc], b, o0, 0, 0, 0);
    }

    #pragma unroll
    for (int r = 0; r < 4; r++) {
        int node = nb0 + quad * 4 + r;
        if (node < n) {
            float s = dinv[node];
            Hout[(size_t)node * NF + ct * 16 + l15] = __float2half(o0[r] * s);
        }
    }
}

// ---------------- agg4: final aggregate (fp32 out); 256 thr, 8 nodes/block ------
__global__ __launch_bounds__(256) void agg4_k(
    const __half* __restrict__ hs, const int* __restrict__ rowptr,
    const int* __restrict__ csr, const float* __restrict__ dinv,
    const float* __restrict__ bias, float* __restrict__ outf, int n)
{
    const int tid = threadIdx.x;
    const int wave = tid >> 6, lane = tid & 63;
    const int g = lane >> 4, fl = lane & 15;
    const int nA = blockIdx.x * 8 + wave * 2;
    if (nA >= n) return;

    floatx4 ac0 = {0.f, 0.f, 0.f, 0.f}, ac1 = {0.f, 0.f, 0.f, 0.f};
    gather2w((const half8*)hs, csr, rowptr, nA, n, g, fl, lane, ac0, ac1);

    if ((g & 1) == 0) {
        int node = nA + (g >> 1);
        if (node < n) {
            float dv = dinv[node];
            const floatx4 bv0 = *(const floatx4*)&bias[fl * 8];
            const floatx4 bv1 = *(const floatx4*)&bias[fl * 8 + 4];
            floatx4 w0, w1;
            w0[0] = dv * ac0[0] + bv0[0]; w0[1] = dv * ac0[1] + bv0[1];
            w0[2] = dv * ac0[2] + bv0[2]; w0[3] = dv * ac0[3] + bv0[3];
            w1[0] = dv * ac1[0] + bv1[0]; w1[1] = dv * ac1[1] + bv1[1];
            w1[2] = dv * ac1[2] + bv1[2]; w1[3] = dv * ac1[3] + bv1[3];
            *(floatx4*)(outf + (size_t)node * NF + fl * 8)     = w0;
            *(floatx4*)(outf + (size_t)node * NF + fl * 8 + 4) = w1;
        }
    }
}

// ---------------- launch ----------------

extern "C" void kernel_launch(void* const* d_in, const int* in_sizes, int n_in,
                              void* d_out, int out_size, void* d_ws, size_t ws_size,
                              hipStream_t stream) {
    const float* x  = (const float*)d_in[0];
    const int*   ei = (const int*)d_in[1];
    const float* W1 = (const float*)d_in[2];
    const float* b1 = (const float*)d_in[3];
    const float* W2 = (const float*)d_in[4];
    const float* b2 = (const float*)d_in[5];
    float* out = (float*)d_out;

    const int N = in_sizes[0] / NF;   // 50000
    const int E = in_sizes[1] / 2;    // 800000
    const int* src = ei;
    const int* dst = ei + E;

    char* ws = (char*)d_ws;
    size_t off = 0;
    auto alloc = [&](size_t bytes) {
        void* p = ws + off;
        off += bytes;
        off = (off + 63) & ~(size_t)63;
        return p;
    };
    unsigned char* pcnt = (unsigned char*)alloc((size_t)KC * N);  // counts->coff
    int*    rowptr  = (int*)alloc((size_t)(N + 1) * 4);   // local prefixes
    int*    rowptr2 = (int*)alloc((size_t)(N + 1) * 4);   // corrected (agg uses)
    int*    csr     = (int*)alloc((size_t)E * 4);
    float*  dinv    = (float*)alloc((size_t)N * 4);
    int*    bsum    = (int*)alloc((size_t)256 * 4);
    __half* WT1     = (__half*)alloc((size_t)NF * NF * 2);
    __half* WT2     = (__half*)alloc((size_t)NF * NF * 2);
    __half* H16     = (__half*)alloc((size_t)N * NF * 2);
    __half* A16     = (__half*)alloc((size_t)N * NF * 2);

    int nb  = (N + 255) / 256;                 // 196 (<=256)
    int Ec  = (((E + KC - 1) / KC) + 3) & ~3;  // chunk size, multiple of 4
    int GB2 = (N + 127) / 128;                 // gemm1 blocks (512 thr)
    int fb  = (N + 15) / 16;                   // aggmm blocks (16 nodes, 512 thr)
    int ab  = (N + 7) / 8;                     // agg4 blocks (8 nodes, 256 thr)

    count2_k<<<KC * NPART, 512, 0, stream>>>(dst, pcnt, E, N, Ec);
    pscan2_k<<<nb + 128, 256, 0, stream>>>(pcnt, dinv, rowptr, bsum, N, N, nb,
                                           W1, W2, WT1, WT2);
    mid_k<<<GB2 + KC * NPART, 512, 0, stream>>>(src, dst, rowptr, pcnt, bsum,
                                                rowptr2, csr, E, N, Ec, nb,
                                                x, WT1, dinv, H16, GB2);
    // fused layer-1 aggregate + layer-2 GEMM (2-node/wave 16B-load gather)
    aggmm_k<<<fb, 512, 0, stream>>>(H16, rowptr2, csr, dinv, b1, WT2, A16, N);
    // final aggregate -> fp32 output
    agg4_k<<<ab, 256, 0, stream>>>(A16, rowptr2, csr, dinv, b2, out, N);
}